// Round 1
// baseline (943.187 us; speedup 1.0000x reference)
//
#include <hip/hip_runtime.h>
#include <hip/hip_bf16.h>

typedef float f32x4 __attribute__((ext_vector_type(4)));
typedef short bf16x8 __attribute__((ext_vector_type(8)));

#define NB 50000
#define NK 32
#define NH 128
#define NL 64

__device__ __forceinline__ unsigned short f2bf(float f) {
    unsigned int u = __float_as_uint(f);
    u += 0x7fffu + ((u >> 16) & 1u);
    return (unsigned short)(u >> 16);
}

__global__ void kl_zero_kernel(float* out) {
    if (threadIdx.x == 0 && blockIdx.x == 0) out[(size_t)NB * NH] = 0.0f;
}

__global__ void __launch_bounds__(256) vibgat_kernel(
    const float* __restrict__ self_feat, const float* __restrict__ neighbor_feat,
    const float* __restrict__ trust_mask, const float* __restrict__ eps,
    const float* __restrict__ pre_g, const float* __restrict__ pre_b,
    const float* __restrict__ W_mu, const float* __restrict__ b_mu,
    const float* __restrict__ W_lv, const float* __restrict__ b_lv,
    const float* __restrict__ post_g, const float* __restrict__ post_b,
    const float* __restrict__ W_q, const float* __restrict__ b_q,
    const float* __restrict__ W_k, const float* __restrict__ b_k,
    const float* __restrict__ W_v, const float* __restrict__ b_v,
    const float* __restrict__ W_o, const float* __restrict__ b_o,
    float* __restrict__ out)
{
    __shared__ unsigned short nn_lds[32 * 128];   // bf16, swizzled, row stride 256B
    __shared__ float muv[32 * 132];               // f32, padded stride 132
    __shared__ unsigned short z_lds[32 * 64];     // bf16, swizzled, row stride 128B
    __shared__ float selff[128];
    __shared__ float qv[64];
    __shared__ float attn_l[32];
    __shared__ float ctxl[64];
    __shared__ float red[4 * 64];
    __shared__ float red2[2 * 128];
    __shared__ float s_preg[128], s_preb[128], s_bo[128];
    __shared__ float s_bmu[64], s_blv[64], s_bk[64], s_bv[64], s_bq[64], s_pg[64], s_pb[64];
    __shared__ float klw[4];

    const int t = threadIdx.x;
    const int w = t >> 6;       // wave id 0..3
    const int l = t & 63;       // lane

    if (t < 128) { s_preg[t] = pre_g[t]; s_preb[t] = pre_b[t]; s_bo[t] = b_o[t]; }
    if (t < 64)  { s_bmu[t] = b_mu[t]; s_blv[t] = b_lv[t]; s_bk[t] = b_k[t];
                   s_bv[t] = b_v[t];  s_bq[t] = b_q[t];  s_pg[t] = post_g[t]; s_pb[t] = post_b[t]; }

    // ---- persistent weight B-fragments in registers ----
    // B frag for mfma_f32_16x16x32_bf16: col n = lane&15 (+tile base), k = 32*s + 8*(lane>>4) + j
    bf16x8 Bml[2][4];   // [nt][kstep]  cols 32w+16nt+(l&15) of [W_mu | W_lv]
    bf16x8 Bkv[2][2];   // [nt][kstep]  cols 32w+16nt+(l&15) of [W_k | W_v]
    {
        const float* Wm = (w < 2) ? W_mu : W_lv;
        int c0 = (w < 2) ? (32 * w + (l & 15)) : (32 * (w - 2) + (l & 15));
        for (int nt = 0; nt < 2; ++nt) {
            int c = c0 + 16 * nt;
            for (int s = 0; s < 4; ++s) {
                int k0 = 32 * s + 8 * (l >> 4);
                bf16x8 f;
#pragma unroll
                for (int j = 0; j < 8; ++j) f[j] = (short)f2bf(Wm[(k0 + j) * 64 + c]);
                Bml[nt][s] = f;
            }
        }
        const float* Wkv_ = (w < 2) ? W_k : W_v;
        for (int nt = 0; nt < 2; ++nt) {
            int c = c0 + 16 * nt;
            for (int s = 0; s < 2; ++s) {
                int k0 = 32 * s + 8 * (l >> 4);
                bf16x8 f;
#pragma unroll
                for (int j = 0; j < 8; ++j) f[j] = (short)f2bf(Wkv_[(k0 + j) * 64 + c]);
                Bkv[nt][s] = f;
            }
        }
    }
    __syncthreads();

    const f32x4 zero4 = {0.f, 0.f, 0.f, 0.f};
    float kl_acc = 0.f;

    for (int b = blockIdx.x; b < NB; b += gridDim.x) {
        // ---------- phase 0: load neighbors, pre-LN, store bf16 A-tile ----------
        {
            int n = t >> 3, cg = (t & 7) * 16;
            const float* src = neighbor_feat + ((size_t)b * NK + n) * NH + cg;
            float x[16];
#pragma unroll
            for (int i = 0; i < 4; ++i) {
                float4 v4 = ((const float4*)src)[i];
                x[4 * i] = v4.x; x[4 * i + 1] = v4.y; x[4 * i + 2] = v4.z; x[4 * i + 3] = v4.w;
            }
            float s1 = 0.f;
#pragma unroll
            for (int i = 0; i < 16; ++i) s1 += x[i];
            s1 += __shfl_xor(s1, 1); s1 += __shfl_xor(s1, 2); s1 += __shfl_xor(s1, 4);
            float mean = s1 * (1.f / 128.f);
            float s2 = 0.f;
#pragma unroll
            for (int i = 0; i < 16; ++i) { float d = x[i] - mean; s2 += d * d; }
            s2 += __shfl_xor(s2, 1); s2 += __shfl_xor(s2, 2); s2 += __shfl_xor(s2, 4);
            float inv = rsqrtf(s2 * (1.f / 128.f) + 1e-5f);
            unsigned short yb[16];
#pragma unroll
            for (int i = 0; i < 16; ++i)
                yb[i] = f2bf((x[i] - mean) * inv * s_preg[cg + i] + s_preb[cg + i]);
            int boff = n * 256 + cg * 2;
            *(int4*)((char*)nn_lds + ((boff) ^ ((n & 7) << 4))) = *(int4*)&yb[0];
            *(int4*)((char*)nn_lds + ((boff + 16) ^ ((n & 7) << 4))) = *(int4*)&yb[8];
            if (t < 32) ((float4*)selff)[t] = ((const float4*)(self_feat + (size_t)b * NH))[t];
        }
        __syncthreads();

        // ---------- phase 1: MFMA mu|lv  [32,128]@[128,128] ----------
        f32x4 acc[2][2];
#pragma unroll
        for (int mt = 0; mt < 2; ++mt)
#pragma unroll
            for (int nt = 0; nt < 2; ++nt) acc[mt][nt] = zero4;
#pragma unroll
        for (int s = 0; s < 4; ++s) {
            bf16x8 A[2];
#pragma unroll
            for (int mt = 0; mt < 2; ++mt) {
                int row = mt * 16 + (l & 15);
                int boff = row * 256 + s * 64 + (l >> 4) * 16;
                A[mt] = *(const bf16x8*)((const char*)nn_lds + (boff ^ ((row & 7) << 4)));
            }
#pragma unroll
            for (int mt = 0; mt < 2; ++mt)
#pragma unroll
                for (int nt = 0; nt < 2; ++nt)
                    acc[mt][nt] = __builtin_amdgcn_mfma_f32_16x16x32_bf16(A[mt], Bml[nt][s], acc[mt][nt], 0, 0, 0);
        }
        // write mu|lv to LDS (C/D: col=lane&15, row=4*(lane>>4)+r)
#pragma unroll
        for (int mt = 0; mt < 2; ++mt)
#pragma unroll
            for (int nt = 0; nt < 2; ++nt)
#pragma unroll
                for (int r = 0; r < 4; ++r) {
                    int row = mt * 16 + 4 * (l >> 4) + r;
                    int col = 32 * w + 16 * nt + (l & 15);
                    muv[row * 132 + col] = acc[mt][nt][r];
                }
        __syncthreads();

        // ---------- phase 3: z = mu + eps*exp(0.5 lv); KL; post-LN; z->bf16 ----------
        {
            int n = t >> 3, l0 = (t & 7) * 8;
            const float* ep = eps + ((size_t)b * NK + n) * NL + l0;
            float4 e0 = ((const float4*)ep)[0], e1 = ((const float4*)ep)[1];
            float ee[8] = {e0.x, e0.y, e0.z, e0.w, e1.x, e1.y, e1.z, e1.w};
            float zr[8];
#pragma unroll
            for (int i = 0; i < 8; ++i) {
                float mu = muv[n * 132 + l0 + i] + s_bmu[l0 + i];
                float lv = muv[n * 132 + 64 + l0 + i] + s_blv[l0 + i];
                float eh = __expf(0.5f * lv);
                zr[i] = mu + ee[i] * eh;
                kl_acc += 1.f + lv - mu * mu - eh * eh;
            }
            float s1 = 0.f;
#pragma unroll
            for (int i = 0; i < 8; ++i) s1 += zr[i];
            s1 += __shfl_xor(s1, 1); s1 += __shfl_xor(s1, 2); s1 += __shfl_xor(s1, 4);
            float mean = s1 * (1.f / 64.f);
            float s2 = 0.f;
#pragma unroll
            for (int i = 0; i < 8; ++i) { float d = zr[i] - mean; s2 += d * d; }
            s2 += __shfl_xor(s2, 1); s2 += __shfl_xor(s2, 2); s2 += __shfl_xor(s2, 4);
            float inv = rsqrtf(s2 * (1.f / 64.f) + 1e-5f);
            unsigned short zb[8];
#pragma unroll
            for (int i = 0; i < 8; ++i) zb[i] = f2bf((zr[i] - mean) * inv * s_pg[l0 + i] + s_pb[l0 + i]);
            int boff = n * 128 + l0 * 2;
            *(int4*)((char*)z_lds + (boff ^ ((n & 7) << 4))) = *(int4*)&zb[0];
        }
        __syncthreads();

        // ---------- phase 4: MFMA k|v  [32,64]@[64,128]; q partials ----------
        f32x4 acc2[2][2];
#pragma unroll
        for (int mt = 0; mt < 2; ++mt)
#pragma unroll
            for (int nt = 0; nt < 2; ++nt) acc2[mt][nt] = zero4;
#pragma unroll
        for (int s = 0; s < 2; ++s) {
            bf16x8 A[2];
#pragma unroll
            for (int mt = 0; mt < 2; ++mt) {
                int row = mt * 16 + (l & 15);
                int boff = row * 128 + s * 64 + (l >> 4) * 16;
                A[mt] = *(const bf16x8*)((const char*)z_lds + (boff ^ ((row & 7) << 4)));
            }
#pragma unroll
            for (int mt = 0; mt < 2; ++mt)
#pragma unroll
                for (int nt = 0; nt < 2; ++nt)
                    acc2[mt][nt] = __builtin_amdgcn_mfma_f32_16x16x32_bf16(A[mt], Bkv[nt][s], acc2[mt][nt], 0, 0, 0);
        }
        // q partial sums: q[l] = sum_h self[h] * W_q[h][l]
        {
            float s = 0.f;
#pragma unroll
            for (int i = 0; i < 32; ++i) {
                int h = w * 32 + i;
                s += selff[h] * W_q[h * 64 + l];
            }
            red[w * 64 + l] = s;
        }
        // write k|v (+bias) into muv
#pragma unroll
        for (int mt = 0; mt < 2; ++mt)
#pragma unroll
            for (int nt = 0; nt < 2; ++nt) {
                int col = 32 * w + 16 * nt + (l & 15);
                float bias = (col < 64) ? s_bk[col] : s_bv[col - 64];
#pragma unroll
                for (int r = 0; r < 4; ++r) {
                    int row = mt * 16 + 4 * (l >> 4) + r;
                    muv[row * 132 + col] = acc2[mt][nt][r] + bias;
                }
            }
        __syncthreads();
        if (t < 64) qv[t] = red[t] + red[64 + t] + red[128 + t] + red[192 + t] + s_bq[t];
        __syncthreads();

        // ---------- phase 6: logits + softmax (wave 0, lanes 0..31) ----------
        if (t < 32) {
            float dot = 0.f;
#pragma unroll
            for (int i = 0; i < 64; ++i) dot += qv[i] * muv[t * 132 + i];
            float logit = dot * 0.125f + __logf(trust_mask[(size_t)b * NK + t] + 1e-6f);
            float m = logit;
#pragma unroll
            for (int msk = 1; msk < 32; msk <<= 1) m = fmaxf(m, __shfl_xor(m, msk));
            float e = __expf(logit - m);
            float ssum = e;
#pragma unroll
            for (int msk = 1; msk < 32; msk <<= 1) ssum += __shfl_xor(ssum, msk);
            attn_l[t] = e / ssum;
        }
        __syncthreads();

        // ---------- phase 7: context = attn @ v ----------
        {
            float s = 0.f;
#pragma unroll
            for (int i = 0; i < 8; ++i) {
                int n = w * 8 + i;
                s += attn_l[n] * muv[n * 132 + 64 + l];
            }
            red[w * 64 + l] = s;
        }
        __syncthreads();
        if (t < 64) ctxl[t] = red[t] + red[64 + t] + red[128 + t] + red[192 + t];
        __syncthreads();

        // ---------- phase 8: comm = ctx @ W_o + b_o ----------
        {
            int h = t & 127, half = t >> 7;
            float s = 0.f;
#pragma unroll
            for (int i = 0; i < 32; ++i) {
                int lj = half * 32 + i;
                s += ctxl[lj] * W_o[lj * 128 + h];
            }
            red2[half * 128 + h] = s;
        }
        __syncthreads();
        if (t < 128) out[(size_t)b * NH + t] = red2[t] + red2[128 + t] + s_bo[t];
        __syncthreads();
    }

    // ---------- KL reduction ----------
#pragma unroll
    for (int msk = 1; msk < 64; msk <<= 1) kl_acc += __shfl_xor(kl_acc, msk);
    if (l == 0) klw[w] = kl_acc;
    __syncthreads();
    if (t == 0) {
        float tot = klw[0] + klw[1] + klw[2] + klw[3];
        atomicAdd(out + (size_t)NB * NH, tot * (-0.5f * 0.001f / ((float)NB * NK)));
    }
}

extern "C" void kernel_launch(void* const* d_in, const int* in_sizes, int n_in,
                              void* d_out, int out_size, void* d_ws, size_t ws_size,
                              hipStream_t stream) {
    const float* self_feat     = (const float*)d_in[0];
    const float* neighbor_feat = (const float*)d_in[1];
    const float* trust_mask    = (const float*)d_in[2];
    const float* eps           = (const float*)d_in[3];
    const float* pre_g  = (const float*)d_in[4];
    const float* pre_b  = (const float*)d_in[5];
    const float* W_mu   = (const float*)d_in[6];
    const float* b_mu   = (const float*)d_in[7];
    const float* W_lv   = (const float*)d_in[8];
    const float* b_lv   = (const float*)d_in[9];
    const float* post_g = (const float*)d_in[10];
    const float* post_b = (const float*)d_in[11];
    const float* W_q    = (const float*)d_in[12];
    const float* b_q    = (const float*)d_in[13];
    const float* W_k    = (const float*)d_in[14];
    const float* b_k    = (const float*)d_in[15];
    const float* W_v    = (const float*)d_in[16];
    const float* b_v    = (const float*)d_in[17];
    const float* W_o    = (const float*)d_in[18];
    const float* b_o    = (const float*)d_in[19];
    float* out = (float*)d_out;

    hipLaunchKernelGGL(kl_zero_kernel, dim3(1), dim3(64), 0, stream, out);
    hipLaunchKernelGGL(vibgat_kernel, dim3(1024), dim3(256), 0, stream,
                       self_feat, neighbor_feat, trust_mask, eps,
                       pre_g, pre_b, W_mu, b_mu, W_lv, b_lv, post_g, post_b,
                       W_q, b_q, W_k, b_k, W_v, b_v, W_o, b_o, out);
}